// Round 3
// baseline (289.208 us; speedup 1.0000x reference)
//
#include <hip/hip_runtime.h>
#include <cstdint>

typedef __bf16 bf16_t;
typedef __attribute__((ext_vector_type(8))) __bf16 bf16x8;
typedef __attribute__((ext_vector_type(4))) __bf16 bf16x4;
typedef __attribute__((ext_vector_type(4))) float f32x4;

#define AS1 __attribute__((address_space(1)))
#define AS3 __attribute__((address_space(3)))

// ---------------------------------------------------------------------------
// gemm256: 256x256-tile NT bf16 GEMM, C[m,n] = sum_k A[m*lda+k]*B[n*ldb+k].
// BK=64, 512 threads = 8 waves (2 M-halves x 4 N-quarters), 128KB LDS
// (2 tile buffers), 4-phase-per-K-tile counted-vmcnt schedule (T3+T4) with
// s_setprio around each 16-MFMA cluster (T5). Round-10 rewrite: all four
// GEMM steps were stuck at the m97-structure ceiling (~717 TF, MfmaUtil 26%,
// one full vmcnt(0) drain per K-step at __syncthreads).
//
// Schedule per K-tile t (buffer pi = t&1; tile t+1 lives in pi^1):
//   P0: ds_read A-q1(t)            | stage B-lo(t+2)->pi | bar | MFMA m0,1 | bar
//   P1: ds_read A-q2(t)            | stage B-hi(t+2)->pi | bar | MFMA m2,3 | bar
//   P2: ds_read A-q3(t)            | s_waitcnt vmcnt(4)  | bar | MFMA m4,5 | bar
//   P3: ds_read B(t+1)+A-q0(t+1)   | stage A-lo/hi(t+2)  | bar | MFMA m6,7 | bar
// Reads run ONE PHASE AHEAD of their MFMA (compiler emits counted lgkmcnt).
// vmcnt(4) proves tiles <= t+1 landed (only the 2 B(t+2) stages are newer);
// the main loop never drains vmcnt to 0. Overwrite safety: B(t+2)->Bs[pi]
// only after B(t)'s last read (P3 of t-1, 2 barriers back); A(t+2)->As[pi]
// only after A-q3(t)'s read (P2, 2 barriers back). Register plan: acc 128 +
// A ping-pong 32 + B per-parity 64 ~ 244 VGPR; launch_bounds(512,2) caps 256.
//
// LDS layout: rows of 8 16B chunks, chunk c of row r at slot c ^ (r&7)
// (pre-swizzled global source; measured conflict-free ds_read_b128).
//
// causal=1: skip block if bn > bm (QK^T lower-triangle 256-tiles; diagonal
//           upper garbage is never read by softmax).
// kLimit=1: Keff = min(K,(bm+1)*256), bm flipped heavy-first. Softmax
//           zero-fills exactly [t+1, (bm+1)*256) -> PV reads only defined P.
//           Keff multiple of 256 -> NT = Keff/64 >= 4 and even (prologue
//           stages 2 tiles; loop is unrolled by 2).
// ---------------------------------------------------------------------------

#define READ_AQ(slot, bb, qidx)                                                \
  _Pragma("unroll")                                                            \
  for (int il = 0; il < 2; il++)                                               \
    _Pragma("unroll")                                                          \
    for (int s2 = 0; s2 < 2; s2++) {                                           \
      const int r_ = wr * 128 + ((qidx) * 2 + il) * 16 + lm;                   \
      aQ[slot][il * 2 + s2] =                                                  \
        *(const bf16x8*)&As[bb][r_ * 64 + (((s2 * 4 + qd) ^ (lm & 7)) << 3)];  \
    }

#define READ_B(pi_, bb)                                                        \
  _Pragma("unroll")                                                            \
  for (int j = 0; j < 4; j++)                                                  \
    _Pragma("unroll")                                                          \
    for (int s2 = 0; s2 < 2; s2++) {                                           \
      const int r_ = wc * 64 + j * 16 + lm;                                    \
      bS[pi_][j * 2 + s2] =                                                    \
        *(const bf16x8*)&Bs[bb][r_ * 64 + (((s2 * 4 + qd) ^ (lm & 7)) << 3)];  \
    }

#define MFMA_PH(p, slot, pi_)                                                  \
  __builtin_amdgcn_s_setprio(1);                                               \
  _Pragma("unroll")                                                            \
  for (int il = 0; il < 2; il++)                                               \
    _Pragma("unroll")                                                          \
    for (int j = 0; j < 4; j++)                                                \
      _Pragma("unroll")                                                        \
      for (int s2 = 0; s2 < 2; s2++)                                           \
        acc[(p) * 2 + il][j] = __builtin_amdgcn_mfma_f32_16x16x32_bf16(        \
            aQ[slot][il * 2 + s2], bS[pi_][j * 2 + s2],                        \
            acc[(p) * 2 + il][j], 0, 0, 0);                                    \
  __builtin_amdgcn_s_setprio(0);

template <typename OutT>
__global__ __launch_bounds__(512, 2)
void gemm256(const bf16_t* __restrict__ A, const bf16_t* __restrict__ B,
             OutT* __restrict__ C, int K, int lda, int ldb, int ldc,
             long sA, long sB, long sC, int causal, int kLimit)
{
  int bm = blockIdx.y;
  const int bn = blockIdx.x;
  if (kLimit) bm = gridDim.y - 1 - bm;   // heavy tiles dispatch first
  if (causal && bn > bm) return;
  A += (long)blockIdx.z * sA;
  B += (long)blockIdx.z * sB;
  C += (long)blockIdx.z * sC;
  const int m0 = bm * 256, n0 = bn * 256;
  int Keff = K;
  if (kLimit) { const int kl = (bm + 1) * 256; if (kl < Keff) Keff = kl; }

  __shared__ bf16_t As[2][256 * 64];   // 32KB each
  __shared__ bf16_t Bs[2][256 * 64];   // 128KB total -> 1 block/CU

  const int tid = threadIdx.x;
  const int wave = tid >> 6, lane = tid & 63;
  const int lm = lane & 15, qd = lane >> 4;
  const int wr = wave >> 2, wc = wave & 3;   // wave -> (M-half, N-quarter)
  const int rowl = lane >> 3;                // 0..7
  const int q = (lane & 7) ^ rowl;           // pre-swizzled global chunk
  const bf16_t* Abase = A + (long)(m0 + wave * 8 + rowl) * lda + q * 8;
  const bf16_t* Bbase = B + (long)(n0 + wave * 8 + rowl) * ldb + q * 8;
  const int woff = wave * 512;               // wave-uniform LDS elem base

  // stage half-tile h (rows h*128..h*128+127) at k-offset kt into buffer b.
  // 2 global_load_lds x 512 threads x 16B = 16KB per call.
  auto stgA = [&](int kt, int b, int h) {
#pragma unroll
    for (int i = 0; i < 2; i++)
      __builtin_amdgcn_global_load_lds(
          (const AS1 void*)(Abase + (long)(h * 128 + i * 64) * lda + kt),
          (AS3 void*)(As[b] + h * 8192 + i * 4096 + woff), 16, 0, 0);
  };
  auto stgB = [&](int kt, int b, int h) {
#pragma unroll
    for (int i = 0; i < 2; i++)
      __builtin_amdgcn_global_load_lds(
          (const AS1 void*)(Bbase + (long)(h * 128 + i * 64) * ldb + kt),
          (AS3 void*)(Bs[b] + h * 8192 + i * 4096 + woff), 16, 0, 0);
  };

  f32x4 acc[8][4] = {};
  bf16x8 aQ[2][4];   // ping-pong A-quarter: [slot][il*2+s]
  bf16x8 bS[2][8];   // per-tile-parity B set: [pi][j*2+s]

  // prologue: tile 0 -> buf0, tile 1 -> buf1 (8 loads each)
  stgB(0, 0, 0);  stgB(0, 0, 1);  stgA(0, 0, 0);  stgA(0, 0, 1);
  stgB(64, 1, 0); stgB(64, 1, 1); stgA(64, 1, 0); stgA(64, 1, 1);
  asm volatile("s_waitcnt vmcnt(8)" ::: "memory");   // tile 0 landed
  __builtin_amdgcn_s_barrier();
  READ_B(0, 0);
  READ_AQ(0, 0, 0);
  __builtin_amdgcn_s_barrier();   // reads issued before any P0 stage lands

  for (int k0 = 0; k0 < Keff; k0 += 128) {
#pragma unroll
    for (int tt = 0; tt < 2; tt++) {              // pi = tt is compile-time
      const int kk = k0 + tt * 64;
      const bool stg = (kk + 128 < Keff);   // stage tile kk+128 -> buf tt
      const bool nxt = (kk + 64 < Keff);    // read tile kk+64 from buf tt^1
      // ---- P0 ----
      READ_AQ(1, tt, 1);
      if (stg) stgB(kk + 128, tt, 0);
      __builtin_amdgcn_s_barrier();
      __builtin_amdgcn_sched_barrier(0);
      MFMA_PH(0, 0, tt);
      __builtin_amdgcn_s_barrier();
      // ---- P1 ----
      READ_AQ(0, tt, 2);
      if (stg) stgB(kk + 128, tt, 1);
      __builtin_amdgcn_s_barrier();
      __builtin_amdgcn_sched_barrier(0);
      MFMA_PH(1, 1, tt);
      __builtin_amdgcn_s_barrier();
      // ---- P2 ----  (the one vmcnt per K-tile; never 0 in steady state)
      READ_AQ(1, tt, 3);
      if (stg) asm volatile("s_waitcnt vmcnt(4)" ::: "memory");
      else     asm volatile("s_waitcnt vmcnt(0)" ::: "memory");
      __builtin_amdgcn_s_barrier();
      __builtin_amdgcn_sched_barrier(0);
      MFMA_PH(2, 0, tt);
      __builtin_amdgcn_s_barrier();
      // ---- P3 ----
      if (nxt) { READ_B(tt ^ 1, tt ^ 1); READ_AQ(0, tt ^ 1, 0); }
      if (stg) { stgA(kk + 128, tt, 0); stgA(kk + 128, tt, 1); }
      __builtin_amdgcn_s_barrier();
      __builtin_amdgcn_sched_barrier(0);
      MFMA_PH(3, 1, tt);
      __builtin_amdgcn_s_barrier();
    }
  }

#pragma unroll
  for (int i = 0; i < 8; i++) {
    const int row = m0 + wr * 128 + i * 16 + qd * 4;
#pragma unroll
    for (int j = 0; j < 4; j++) {
      const int col = n0 + wc * 64 + j * 16 + lm;
#pragma unroll
      for (int r = 0; r < 4; r++)
        C[(long)(row + r) * ldc + col] = (OutT)acc[i][j][r];
    }
  }
}

// ---------------------------------------------------------------------------
// Fused prep (ONE dispatch): blocks [0,8192) convert X fp32->bf16 (float4
// loads); blocks [8192, 8192+3072) transpose+convert Wq/Wk/Wv into
// WT[out][in] bf16 (32x32 tiles, 256 threads, 4 rows/thread).
// ---------------------------------------------------------------------------
__global__ __launch_bounds__(256)
void prep(const float* __restrict__ X, bf16_t* __restrict__ Xb,
          const float* __restrict__ wq, const float* __restrict__ wk,
          const float* __restrict__ wv, bf16_t* __restrict__ WT)
{
  const int b = blockIdx.x;
  if (b < 8192) {                       // X -> bf16, 4 floats/thread
    const int i = b * 256 + threadIdx.x;
    const float4 f = ((const float4*)X)[i];
    bf16x4 o = {(bf16_t)f.x, (bf16_t)f.y, (bf16_t)f.z, (bf16_t)f.w};
    ((bf16x4*)Xb)[i] = o;
    return;
  }
  const int wid = b - 8192;             // 0..3071
  const int z = wid >> 10;              // which W
  const int t = wid & 1023;             // tile id, 32x32 grid of 32x32 tiles
  const int tix = t & 31, tiy = t >> 5;
  const float* W = (z == 0) ? wq : (z == 1) ? wk : wv;
  bf16_t* O = WT + (long)z * 1024 * 1024;

  __shared__ float tile[32][33];
  const int x = threadIdx.x & 31, y0 = threadIdx.x >> 5;
#pragma unroll
  for (int r = 0; r < 4; r++) {         // read: coalesced over out dim (x)
    const int y = y0 + r * 8;
    tile[y][x] = W[(long)(tiy * 32 + y) * 1024 + (tix * 32 + x)];
  }
  __syncthreads();
#pragma unroll
  for (int r = 0; r < 4; r++) {         // write: coalesced over in dim (x)
    const int y = y0 + r * 8;
    O[(long)(tix * 32 + y) * 1024 + (tiy * 32 + x)] = (bf16_t)tile[x][y];
  }
}

// ---------------------------------------------------------------------------
// In-place causal softmax over S rows (bf16, ld=2048). One block per row.
// logits = S/32; writes P = softmax, zeros above the diagonal.
// Loads only j <= t; stores only j < kend = ((t>>8)+1)*256 (256-granular to
// match the 256-row PV tiles: kend == Keff exactly, so PV reads only
// softmax-defined P).
// ---------------------------------------------------------------------------
__global__ __launch_bounds__(256)
void softmax_causal(bf16_t* __restrict__ S)
{
  const int row = blockIdx.x;
  const int t = row & 2047;
  const int kend = ((t >> 8) + 1) << 8;
  bf16_t* Sr = S + (long)row * 2048;
  const int base = threadIdx.x * 8;

  uint4 u = {0, 0, 0, 0};
  if (base <= t) u = *(const uint4*)(Sr + base);
  const unsigned short* up = (const unsigned short*)&u;
  float v[8];
  float m = -3.0e38f;
#pragma unroll
  for (int j = 0; j < 8; j++) {
    const float x = __uint_as_float(((unsigned)up[j]) << 16);  // bf16 -> f32
    v[j] = (base + j <= t) ? x : -3.0e38f;
    m = fmaxf(m, v[j]);
  }
#pragma unroll
  for (int off = 32; off > 0; off >>= 1) m = fmaxf(m, __shfl_xor(m, off));
  __shared__ float redm[4], redl[4];
  const int wave = threadIdx.x >> 6, lane = threadIdx.x & 63;
  if (lane == 0) redm[wave] = m;
  __syncthreads();
  m = fmaxf(fmaxf(redm[0], redm[1]), fmaxf(redm[2], redm[3]));

  float p[8], l = 0.f;
#pragma unroll
  for (int j = 0; j < 8; j++) {
    p[j] = (base + j <= t) ? __expf((v[j] - m) * 0.03125f) : 0.f;
    l += p[j];
  }
#pragma unroll
  for (int off = 32; off > 0; off >>= 1) l += __shfl_xor(l, off);
  if (lane == 0) redl[wave] = l;
  __syncthreads();
  l = (redl[0] + redl[1]) + (redl[2] + redl[3]);
  const float rl = 1.0f / l;

  if (base < kend) {
    uint4 w;
    unsigned* wp = (unsigned*)&w;
#pragma unroll
    for (int h = 0; h < 4; h++) {
      bf16_t a = (bf16_t)(p[2 * h] * rl);
      bf16_t b = (bf16_t)(p[2 * h + 1] * rl);
      wp[h] = (unsigned)__builtin_bit_cast(unsigned short, a) |
              ((unsigned)__builtin_bit_cast(unsigned short, b) << 16);
    }
    *(uint4*)(Sr + base) = w;
  }
}

// ---------------------------------------------------------------------------
extern "C" void kernel_launch(void* const* d_in, const int* in_sizes, int n_in,
                              void* d_out, int out_size, void* d_ws, size_t ws_size,
                              hipStream_t stream)
{
  const float* X  = (const float*)d_in[0];  // [4,2048,1024]
  const float* Wq = (const float*)d_in[1];  // [1024,1024] (in,out)
  const float* Wk = (const float*)d_in[2];
  const float* Wv = (const float*)d_in[3];
  float* out = (float*)d_out;               // [4,2048,1024]

  // workspace layout (bytes): QK 33.5M | VT 16.8M | WT 6.3M | {Xb 16.8M / S 33.5M overlap}
  char* p = (char*)d_ws;
  bf16_t* QK = (bf16_t*)p;  p += (size_t)8192 * 2048 * 2;   // [8192, 2048]  Q|K
  bf16_t* VT = (bf16_t*)p;  p += (size_t)1024 * 8192 * 2;   // [1024, 8192]  V^T
  bf16_t* WT = (bf16_t*)p;  p += (size_t)3072 * 1024 * 2;   // [3072, 1024]  Wq^T|Wk^T|Wv^T
  bf16_t* Xb = (bf16_t*)p;                                  // [8192, 1024]  (dead before S)
  bf16_t* S  = (bf16_t*)p;                                  // [4][2048,2048] scores->P

  // 1) fused prep: X -> bf16  +  W -> WT (bf16, transposed)
  prep<<<8192 + 3072, 256, 0, stream>>>(X, Xb, Wq, Wk, Wv, WT);
  // 2) QK = Xb @ [Wq|Wk]   M=8192 N=2048 K=1024   (256 blocks, 256^2 8-phase)
  gemm256<bf16_t><<<dim3(8, 32, 1), 512, 0, stream>>>(
      Xb, WT, QK, 1024, 1024, 1024, 2048, 0, 0, 0, 0, 0);
  // 3) VT = WvT @ Xb^T     M=1024 N=8192 K=1024   (128 blocks)
  gemm256<bf16_t><<<dim3(32, 4, 1), 512, 0, stream>>>(
      WT + (long)2048 * 1024, Xb, VT, 1024, 1024, 1024, 8192, 0, 0, 0, 0, 0);
  // 4) S = Q @ K^T per batch, 256x256 lower-tri tiles (144 active)
  gemm256<bf16_t><<<dim3(8, 8, 4), 512, 0, stream>>>(
      QK, QK + 1024, S, 1024, 2048, 2048, 2048,
      (long)2048 * 2048, (long)2048 * 2048, (long)2048 * 2048, 1, 0);
  // 5) in-place causal softmax (256-granular truncated IO)
  softmax_causal<<<8192, 256, 0, stream>>>(S);
  // 6) O = P @ V (NT vs V^T), 256-row tiles, Keff=(bm+1)*256, heavy-first
  gemm256<float><<<dim3(4, 8, 4), 512, 0, stream>>>(
      S, VT, out, 2048, 2048, 8192, 1024,
      (long)2048 * 2048, 2048, (long)2048 * 1024, 0, 1);
}

// Round 4
// 249.753 us; speedup vs baseline: 1.1580x; 1.1580x over previous
//
#include <hip/hip_runtime.h>
#include <cstdint>

typedef __bf16 bf16_t;
typedef __attribute__((ext_vector_type(8))) __bf16 bf16x8;
typedef __attribute__((ext_vector_type(4))) __bf16 bf16x4;
typedef __attribute__((ext_vector_type(4))) float f32x4;

#define AS1 __attribute__((address_space(1)))
#define AS3 __attribute__((address_space(3)))

// ---------------------------------------------------------------------------
// Big-tile NT bf16 GEMM: C[m,n] = sum_k A[m*lda+k] * B[n*ldb+k]
// Tile 128x128, BK=64, 256 threads, DOUBLE-BUFFERED LDS (64KB, 2 blocks/CU).
// One barrier/iter; prefetch for tile k+1 issued right after it. 717 TF
// measured. PROVEN — do not touch (rounds 9/10 experiments both regressed
// other parts; this kernel's numbers were stable every round).
//
// LDS layout: rows of 8 16B-chunks, chunk q of row r at slot q ^ (r&7)
// (XOR swizzle): per-row-contiguous global reads + conflict-free
// ds_read_b128 (measured SQ_LDS_BANK_CONFLICT = 0).
// ---------------------------------------------------------------------------
template <typename OutT>
__global__ __launch_bounds__(256)
void gemm_nt(const bf16_t* __restrict__ A, const bf16_t* __restrict__ B,
             OutT* __restrict__ C, int K, int lda, int ldb, int ldc)
{
  const int bm = blockIdx.y, bn = blockIdx.x;
  const int m0 = bm * 128, n0 = bn * 128;

  __shared__ bf16_t As[2][128 * 64];  // 16KB each
  __shared__ bf16_t Bs[2][128 * 64];

  const int tid = threadIdx.x;
  const int wave = tid >> 6, lane = tid & 63;
  const int lm = lane & 15, qd = lane >> 4;
  const int wm = (wave >> 1) * 64, wn = (wave & 1) * 64;

  const int rowl = lane >> 3;           // 0..7
  const int q = (lane & 7) ^ rowl;      // swizzled chunk within row
  const bf16_t* Abase = A + (long)(m0 + wave * 8 + rowl) * lda + q * 8;
  const bf16_t* Bbase = B + (long)(n0 + wave * 8 + rowl) * ldb + q * 8;
  const int woff = wave * 512;

  auto stage = [&](int k0, int b) {
#pragma unroll
    for (int i = 0; i < 4; i++) {
      __builtin_amdgcn_global_load_lds((const AS1 void*)(Abase + (long)i * 32 * lda + k0),
                                       (AS3 void*)(As[b] + woff + i * 2048), 16, 0, 0);
      __builtin_amdgcn_global_load_lds((const AS1 void*)(Bbase + (long)i * 32 * ldb + k0),
                                       (AS3 void*)(Bs[b] + woff + i * 2048), 16, 0, 0);
    }
  };

  f32x4 acc[4][4] = {};

  stage(0, 0);
  int buf = 0;
  for (int k0 = 0; k0 < K; k0 += 64) {
    __syncthreads();                   // drains tile-k loads (issued 1 iter ago)
    if (k0 + 64 < K) stage(k0 + 64, buf ^ 1);
#pragma unroll
    for (int s = 0; s < 2; s++) {
      bf16x8 aF[4], bF[4];
#pragma unroll
      for (int i = 0; i < 4; i++) {
        const int r = wm + i * 16 + lm;
        aF[i] = *(const bf16x8*)&As[buf][r * 64 + (((s * 4 + qd) ^ (lm & 7)) << 3)];
      }
#pragma unroll
      for (int j = 0; j < 4; j++) {
        const int r = wn + j * 16 + lm;
        bF[j] = *(const bf16x8*)&Bs[buf][r * 64 + (((s * 4 + qd) ^ (lm & 7)) << 3)];
      }
#pragma unroll
      for (int i = 0; i < 4; i++)
#pragma unroll
        for (int j = 0; j < 4; j++)
          acc[i][j] = __builtin_amdgcn_mfma_f32_16x16x32_bf16(aF[i], bF[j], acc[i][j], 0, 0, 0);
    }
    buf ^= 1;
  }

#pragma unroll
  for (int i = 0; i < 4; i++) {
    const int row = m0 + wm + i * 16 + qd * 4;
#pragma unroll
    for (int j = 0; j < 4; j++) {
      const int col = n0 + wn + j * 16 + lm;
#pragma unroll
      for (int r = 0; r < 4; r++)
        C[(long)(row + r) * ldc + col] = (OutT)acc[i][j][r];
    }
  }
}

// ---------------------------------------------------------------------------
// Causal 128x128 NT GEMM — identical structure to gemm_nt plus batch strides
// and two causal modes. 128 tiles (NOT 256): causal work is load-imbalanced;
// per-block work must stay small (round-11 post-mortem: 256-tile causal had a
// 268 MF diagonal block = 44us single-CU makespan).
//
// causal=1:  skip block if bn > bm (S = QK^T lower-triangle 128-tiles).
// kLimit=1:  Keff = min(K, (bm+1)*128), bm flipped heavy-first. Matches
//            softmax's 128-granular zero-fill -> no uninitialized P reads.
// ---------------------------------------------------------------------------
template <typename OutT>
__global__ __launch_bounds__(256)
void gemm_ntc(const bf16_t* __restrict__ A, const bf16_t* __restrict__ B,
              OutT* __restrict__ C, int K, int lda, int ldb, int ldc,
              long sA, long sB, long sC, int causal, int kLimit)
{
  int bm = blockIdx.y;
  const int bn = blockIdx.x;
  if (kLimit) bm = gridDim.y - 1 - bm;   // heavy tiles dispatch first
  if (causal && bn > bm) return;
  A += (long)blockIdx.z * sA;
  B += (long)blockIdx.z * sB;
  C += (long)blockIdx.z * sC;
  const int m0 = bm * 128, n0 = bn * 128;
  int Keff = K;
  if (kLimit) { const int kl = (bm + 1) * 128; if (kl < Keff) Keff = kl; }

  __shared__ bf16_t As[2][128 * 64];  // 16KB each
  __shared__ bf16_t Bs[2][128 * 64];

  const int tid = threadIdx.x;
  const int wave = tid >> 6, lane = tid & 63;
  const int lm = lane & 15, qd = lane >> 4;
  const int wm = (wave >> 1) * 64, wn = (wave & 1) * 64;

  const int rowl = lane >> 3;           // 0..7
  const int q = (lane & 7) ^ rowl;      // swizzled chunk within row
  const bf16_t* Abase = A + (long)(m0 + wave * 8 + rowl) * lda + q * 8;
  const bf16_t* Bbase = B + (long)(n0 + wave * 8 + rowl) * ldb + q * 8;
  const int woff = wave * 512;

  auto stage = [&](int k0, int b) {
#pragma unroll
    for (int i = 0; i < 4; i++) {
      __builtin_amdgcn_global_load_lds((const AS1 void*)(Abase + (long)i * 32 * lda + k0),
                                       (AS3 void*)(As[b] + woff + i * 2048), 16, 0, 0);
      __builtin_amdgcn_global_load_lds((const AS1 void*)(Bbase + (long)i * 32 * ldb + k0),
                                       (AS3 void*)(Bs[b] + woff + i * 2048), 16, 0, 0);
    }
  };

  f32x4 acc[4][4] = {};

  stage(0, 0);
  int buf = 0;
  for (int k0 = 0; k0 < Keff; k0 += 64) {
    __syncthreads();                   // drains tile-k loads (issued 1 iter ago)
    if (k0 + 64 < Keff) stage(k0 + 64, buf ^ 1);
#pragma unroll
    for (int s = 0; s < 2; s++) {
      bf16x8 aF[4], bF[4];
#pragma unroll
      for (int i = 0; i < 4; i++) {
        const int r = wm + i * 16 + lm;
        aF[i] = *(const bf16x8*)&As[buf][r * 64 + (((s * 4 + qd) ^ (lm & 7)) << 3)];
      }
#pragma unroll
      for (int j = 0; j < 4; j++) {
        const int r = wn + j * 16 + lm;
        bF[j] = *(const bf16x8*)&Bs[buf][r * 64 + (((s * 4 + qd) ^ (lm & 7)) << 3)];
      }
#pragma unroll
      for (int i = 0; i < 4; i++)
#pragma unroll
        for (int j = 0; j < 4; j++)
          acc[i][j] = __builtin_amdgcn_mfma_f32_16x16x32_bf16(aF[i], bF[j], acc[i][j], 0, 0, 0);
    }
    buf ^= 1;
  }

#pragma unroll
  for (int i = 0; i < 4; i++) {
    const int row = m0 + wm + i * 16 + qd * 4;
#pragma unroll
    for (int j = 0; j < 4; j++) {
      const int col = n0 + wn + j * 16 + lm;
#pragma unroll
      for (int r = 0; r < 4; r++)
        C[(long)(row + r) * ldc + col] = (OutT)acc[i][j][r];
    }
  }
}

// ---------------------------------------------------------------------------
// gemm256 v2: 256x256-tile NT bf16 GEMM, faithful m201 8-phase port.
// Used ONLY for the dense step 2 (256 blocks = exactly 1/CU; causal steps
// stay on 128 tiles for load balance). 512 thr = 8 waves (2M x 4N), per-wave
// C = 128x64. BK=64, 4 phases per K-tile, 2 K-tiles per loop iter.
//
// Phase p (mp=p>>1, np=p&1) of tile t (buf d=t&1, other=dn):
//   12 ds_reads: A quadrant (4 M-frags mp*4.., 2 k-slices) + B (2 N-frags
//   np*2.., 2 k-slices)  ->  16 MFMA after barrier+lgkmcnt(0).
//   stages: p0: A-chunks23(t+1)->dn | p1: B-chunks23(t+1)->dn
//           p2: A-chunks01(t+2)->d  | p3: B-chunks01(t+2)->d + vmcnt(4)
//   then: s_barrier; lgkmcnt(0); sched_barrier; setprio(1); 16 MFMA;
//         setprio(0); s_barrier.
//
// DEATH-SCHEDULED LDS CHUNKS (race-free by construction, not by latency):
// chunks are 64-row LDS regions ordered so each staged chunk's last ds_read
// completed (lgkmcnt(0)) in an EARLIER phase than the stage issue:
//   As chunk c holds global rows (c&1)*128 + (c>>1)*64 .. +63
//     -> chunks {0,1} read at p0/p1 (mp=0), dead before p2 stage. ✓
//   Bs chunk c holds n: (c&1)*128 + (w>>5)*64 + (c>>1)*32 + (w&31)
//     -> chunks {0,1} (np=0) read at p0/p2... staged at p3 of NEXT parity
//        context; chunks {2,3} (np=1) read p1/p3, staged at p1 of next tile,
//        after their p3 lgkmcnt of the previous tile. ✓
// vmcnt(4) at p3 proves tile t+1 (8 oldest of 12 outstanding) landed before
// its first read at p0 of t+1; steady state never drains vmcnt to 0 (T4).
// Prologue primes exactly the steady-state in-flight pattern.
// ---------------------------------------------------------------------------
template <typename OutT>
__global__ __launch_bounds__(512, 2)
void gemm256(const bf16_t* __restrict__ A, const bf16_t* __restrict__ B,
             OutT* __restrict__ C, int K, int lda, int ldb, int ldc)
{
  const int bm = blockIdx.y, bn = blockIdx.x;
  const int m0 = bm * 256, n0 = bn * 256;

  __shared__ bf16_t As[2][256 * 64];   // 32KB each
  __shared__ bf16_t Bs[2][256 * 64];   // 128KB total -> 1 block/CU

  const int tid = threadIdx.x;
  const int wave = tid >> 6, lane = tid & 63;
  const int lm = lane & 15, qd = lane >> 4;
  const int wr = wave >> 2, wc = wave & 3;   // (M-half, N-quarter)
  const int wch = wc >> 1, wcl = wc & 1;
  const int rowl = lane >> 3;                // 0..7
  const int q = (lane & 7) ^ rowl;           // pre-swizzled global chunk
  const int woff = wave * 512;               // wave-uniform LDS elem base

  // stage one 64-row chunk c of A/B at k-offset kt into buffer b.
  // 1 global_load_lds per wave (8 rows/wave x 64k x 2B = 1KB).
  auto stgAc = [&](int kt, int b, int c) {
    const int grow = m0 + ((c & 1) << 7) + ((c >> 1) << 6) + wave * 8 + rowl;
    __builtin_amdgcn_global_load_lds(
        (const AS1 void*)(A + (long)grow * lda + q * 8 + kt),
        (AS3 void*)(As[b] + c * 4096 + woff), 16, 0, 0);
  };
  auto stgBc = [&](int kt, int b, int c) {
    const int gn = n0 + ((c & 1) << 7) + ((wave >> 2) << 6) + ((c >> 1) << 5) +
                   (wave & 3) * 8 + rowl;
    __builtin_amdgcn_global_load_lds(
        (const AS1 void*)(B + (long)gn * ldb + q * 8 + kt),
        (AS3 void*)(Bs[b] + c * 4096 + woff), 16, 0, 0);
  };

  f32x4 acc[8][4] = {};

#define PHASE256(p, d, dn, kk, stg1, stg2)                                     \
  {                                                                            \
    constexpr int mp = (p) >> 1, np = (p) & 1;                                 \
    bf16x8 aF[4][2], bF[2][2];                                                 \
    _Pragma("unroll")                                                          \
    for (int mi = 0; mi < 4; mi++)                                             \
      _Pragma("unroll")                                                        \
      for (int s2 = 0; s2 < 2; s2++) {                                         \
        const int r_ = (wr + 2 * mp) * 64 + mi * 16 + lm;                      \
        aF[mi][s2] =                                                           \
          *(const bf16x8*)&As[d][r_ * 64 + (((s2 * 4 + qd) ^ (lm & 7)) << 3)]; \
      }                                                                        \
    _Pragma("unroll")                                                          \
    for (int nj = 0; nj < 2; nj++)                                             \
      _Pragma("unroll")                                                        \
      for (int s2 = 0; s2 < 2; s2++) {                                         \
        const int r_ = (np * 2 + wch) * 64 + wcl * 32 + nj * 16 + lm;          \
        bF[nj][s2] =                                                           \
          *(const bf16x8*)&Bs[d][r_ * 64 + (((s2 * 4 + qd) ^ (lm & 7)) << 3)]; \
      }                                                                        \
    if ((p) == 0 && (stg1)) { stgAc((kk) + 64, dn, 2); stgAc((kk) + 64, dn, 3); } \
    if ((p) == 1 && (stg1)) { stgBc((kk) + 64, dn, 2); stgBc((kk) + 64, dn, 3); } \
    if ((p) == 2 && (stg2)) { stgAc((kk) + 128, d, 0); stgAc((kk) + 128, d, 1); } \
    if ((p) == 3 && (stg2)) { stgBc((kk) + 128, d, 0); stgBc((kk) + 128, d, 1); } \
    if ((p) == 3) {                                                            \
      if (stg2) asm volatile("s_waitcnt vmcnt(4)" ::: "memory");               \
      else      asm volatile("s_waitcnt vmcnt(0)" ::: "memory");               \
    }                                                                          \
    __builtin_amdgcn_s_barrier();                                              \
    asm volatile("s_waitcnt lgkmcnt(0)" ::: "memory");                         \
    __builtin_amdgcn_sched_barrier(0);                                         \
    __builtin_amdgcn_s_setprio(1);                                             \
    _Pragma("unroll")                                                          \
    for (int mi = 0; mi < 4; mi++)                                             \
      _Pragma("unroll")                                                        \
      for (int nj = 0; nj < 2; nj++)                                           \
        _Pragma("unroll")                                                      \
        for (int s2 = 0; s2 < 2; s2++)                                         \
          acc[mp * 4 + mi][np * 2 + nj] =                                      \
              __builtin_amdgcn_mfma_f32_16x16x32_bf16(                         \
                  aF[mi][s2], bF[nj][s2], acc[mp * 4 + mi][np * 2 + nj],       \
                  0, 0, 0);                                                    \
    __builtin_amdgcn_s_setprio(0);                                             \
    __builtin_amdgcn_s_barrier();                                              \
  }

  // prologue: tile0 fully (8 instrs), tile1 chunks A01+B01 (4 instrs).
  // vmcnt(4): tile0 landed; tile1's A01/B01 (the steady-state pattern) in
  // flight.
  stgAc(0, 0, 0); stgAc(0, 0, 1); stgAc(0, 0, 2); stgAc(0, 0, 3);
  stgBc(0, 0, 0); stgBc(0, 0, 1); stgBc(0, 0, 2); stgBc(0, 0, 3);
  stgAc(64, 1, 0); stgAc(64, 1, 1);
  stgBc(64, 1, 0); stgBc(64, 1, 1);
  asm volatile("s_waitcnt vmcnt(4)" ::: "memory");
  __builtin_amdgcn_s_barrier();

  for (int kk = 0; kk < K; kk += 128) {
    const bool s1a = (kk + 64  < K);
    const bool s2a = (kk + 128 < K);
    const bool s2b = (kk + 192 < K);
    // tile parity 0
    PHASE256(0, 0, 1, kk, s1a, s2a)
    PHASE256(1, 0, 1, kk, s1a, s2a)
    PHASE256(2, 0, 1, kk, s1a, s2a)
    PHASE256(3, 0, 1, kk, s1a, s2a)
    // tile parity 1
    PHASE256(0, 1, 0, kk + 64, s2a, s2b)
    PHASE256(1, 1, 0, kk + 64, s2a, s2b)
    PHASE256(2, 1, 0, kk + 64, s2a, s2b)
    PHASE256(3, 1, 0, kk + 64, s2a, s2b)
  }
#undef PHASE256

#pragma unroll
  for (int i = 0; i < 8; i++) {
    const int row = m0 + wr * 128 + i * 16 + qd * 4;
#pragma unroll
    for (int j = 0; j < 4; j++) {
      const int col = n0 + wc * 64 + j * 16 + lm;
#pragma unroll
      for (int r = 0; r < 4; r++)
        C[(long)(row + r) * ldc + col] = (OutT)acc[i][j][r];
    }
  }
}

// ---------------------------------------------------------------------------
// Fused prep (ONE dispatch): blocks [0,8192) convert X fp32->bf16 (float4
// loads); blocks [8192, 8192+3072) transpose+convert Wq/Wk/Wv into
// WT[out][in] bf16 (32x32 tiles, 256 threads, 4 rows/thread).
// ---------------------------------------------------------------------------
__global__ __launch_bounds__(256)
void prep(const float* __restrict__ X, bf16_t* __restrict__ Xb,
          const float* __restrict__ wq, const float* __restrict__ wk,
          const float* __restrict__ wv, bf16_t* __restrict__ WT)
{
  const int b = blockIdx.x;
  if (b < 8192) {                       // X -> bf16, 4 floats/thread
    const int i = b * 256 + threadIdx.x;
    const float4 f = ((const float4*)X)[i];
    bf16x4 o = {(bf16_t)f.x, (bf16_t)f.y, (bf16_t)f.z, (bf16_t)f.w};
    ((bf16x4*)Xb)[i] = o;
    return;
  }
  const int wid = b - 8192;             // 0..3071
  const int z = wid >> 10;              // which W
  const int t = wid & 1023;             // tile id, 32x32 grid of 32x32 tiles
  const int tix = t & 31, tiy = t >> 5;
  const float* W = (z == 0) ? wq : (z == 1) ? wk : wv;
  bf16_t* O = WT + (long)z * 1024 * 1024;

  __shared__ float tile[32][33];
  const int x = threadIdx.x & 31, y0 = threadIdx.x >> 5;
#pragma unroll
  for (int r = 0; r < 4; r++) {         // read: coalesced over out dim (x)
    const int y = y0 + r * 8;
    tile[y][x] = W[(long)(tiy * 32 + y) * 1024 + (tix * 32 + x)];
  }
  __syncthreads();
#pragma unroll
  for (int r = 0; r < 4; r++) {         // write: coalesced over in dim (x)
    const int y = y0 + r * 8;
    O[(long)(tix * 32 + y) * 1024 + (tiy * 32 + x)] = (bf16_t)tile[x][y];
  }
}

// ---------------------------------------------------------------------------
// In-place causal softmax over S rows (bf16, ld=2048). One block per row.
// logits = S/32; writes P = softmax, zeros above the diagonal.
// Loads only j <= t; stores only j < kend = ((t>>7)+1)*128 — beyond kend P
// is never read by the PV GEMM (Keff stops there); [t+1, kend) gets zeros.
// ---------------------------------------------------------------------------
__global__ __launch_bounds__(256)
void softmax_causal(bf16_t* __restrict__ S)
{
  const int row = blockIdx.x;
  const int t = row & 2047;
  const int kend = ((t >> 7) + 1) << 7;
  bf16_t* Sr = S + (long)row * 2048;
  const int base = threadIdx.x * 8;

  uint4 u = {0, 0, 0, 0};
  if (base <= t) u = *(const uint4*)(Sr + base);
  const unsigned short* up = (const unsigned short*)&u;
  float v[8];
  float m = -3.0e38f;
#pragma unroll
  for (int j = 0; j < 8; j++) {
    const float x = __uint_as_float(((unsigned)up[j]) << 16);  // bf16 -> f32
    v[j] = (base + j <= t) ? x : -3.0e38f;
    m = fmaxf(m, v[j]);
  }
#pragma unroll
  for (int off = 32; off > 0; off >>= 1) m = fmaxf(m, __shfl_xor(m, off));
  __shared__ float redm[4], redl[4];
  const int wave = threadIdx.x >> 6, lane = threadIdx.x & 63;
  if (lane == 0) redm[wave] = m;
  __syncthreads();
  m = fmaxf(fmaxf(redm[0], redm[1]), fmaxf(redm[2], redm[3]));

  float p[8], l = 0.f;
#pragma unroll
  for (int j = 0; j < 8; j++) {
    p[j] = (base + j <= t) ? __expf((v[j] - m) * 0.03125f) : 0.f;
    l += p[j];
  }
#pragma unroll
  for (int off = 32; off > 0; off >>= 1) l += __shfl_xor(l, off);
  if (lane == 0) redl[wave] = l;
  __syncthreads();
  l = (redl[0] + redl[1]) + (redl[2] + redl[3]);
  const float rl = 1.0f / l;

  if (base < kend) {
    uint4 w;
    unsigned* wp = (unsigned*)&w;
#pragma unroll
    for (int h = 0; h < 4; h++) {
      bf16_t a = (bf16_t)(p[2 * h] * rl);
      bf16_t b = (bf16_t)(p[2 * h + 1] * rl);
      wp[h] = (unsigned)__builtin_bit_cast(unsigned short, a) |
              ((unsigned)__builtin_bit_cast(unsigned short, b) << 16);
    }
    *(uint4*)(Sr + base) = w;
  }
}

// ---------------------------------------------------------------------------
extern "C" void kernel_launch(void* const* d_in, const int* in_sizes, int n_in,
                              void* d_out, int out_size, void* d_ws, size_t ws_size,
                              hipStream_t stream)
{
  const float* X  = (const float*)d_in[0];  // [4,2048,1024]
  const float* Wq = (const float*)d_in[1];  // [1024,1024] (in,out)
  const float* Wk = (const float*)d_in[2];
  const float* Wv = (const float*)d_in[3];
  float* out = (float*)d_out;               // [4,2048,1024]

  // workspace layout (bytes): QK 33.5M | VT 16.8M | WT 6.3M | {Xb 16.8M / S 33.5M overlap}
  char* p = (char*)d_ws;
  bf16_t* QK = (bf16_t*)p;  p += (size_t)8192 * 2048 * 2;   // [8192, 2048]  Q|K
  bf16_t* VT = (bf16_t*)p;  p += (size_t)1024 * 8192 * 2;   // [1024, 8192]  V^T
  bf16_t* WT = (bf16_t*)p;  p += (size_t)3072 * 1024 * 2;   // [3072, 1024]  Wq^T|Wk^T|Wv^T
  bf16_t* Xb = (bf16_t*)p;                                  // [8192, 1024]  (dead before S)
  bf16_t* S  = (bf16_t*)p;                                  // [4][2048,2048] scores->P

  // 1) fused prep: X -> bf16  +  W -> WT (bf16, transposed)
  prep<<<8192 + 3072, 256, 0, stream>>>(X, Xb, Wq, Wk, Wv, WT);
  // 2) QK = Xb @ [Wq|Wk]   M=8192 N=2048 K=1024  (256 blocks = 1/CU, 8-phase)
  gemm256<bf16_t><<<dim3(8, 32), 512, 0, stream>>>(
      Xb, WT, QK, 1024, 1024, 1024, 2048);
  // 3) VT = WvT @ Xb^T     M=1024 N=8192 K=1024   (512 blocks, dbuf 128-tile)
  gemm_nt<bf16_t><<<dim3(64, 8), 256, 0, stream>>>(
      WT + (long)2048 * 1024, Xb, VT, 1024, 1024, 1024, 8192);
  // 4) S = Q @ K^T per batch, 128x128 lower-tri tiles (544 active), dbuf
  gemm_ntc<bf16_t><<<dim3(16, 16, 4), 256, 0, stream>>>(
      QK, QK + 1024, S, 1024, 2048, 2048, 2048,
      (long)2048 * 2048, (long)2048 * 2048, (long)2048 * 2048, 1, 0);
  // 5) in-place causal softmax (128-granular truncated IO)
  softmax_causal<<<8192, 256, 0, stream>>>(S);
  // 6) O = P @ V (NT vs V^T), 128-row tiles, Keff=(bm+1)*128, heavy-first
  gemm_ntc<float><<<dim3(8, 16, 4), 256, 0, stream>>>(
      S, VT, out, 2048, 2048, 8192, 1024,
      (long)2048 * 2048, 2048, (long)2048 * 1024, 0, 1);
}

// Round 6
// 249.220 us; speedup vs baseline: 1.1605x; 1.0021x over previous
//
#include <hip/hip_runtime.h>
#include <cstdint>

typedef __bf16 bf16_t;
typedef __attribute__((ext_vector_type(8))) __bf16 bf16x8;
typedef __attribute__((ext_vector_type(4))) __bf16 bf16x4;
typedef __attribute__((ext_vector_type(4))) float f32x4;

#define AS1 __attribute__((address_space(1)))
#define AS3 __attribute__((address_space(3)))

// ---------------------------------------------------------------------------
// Big-tile NT bf16 GEMM: C[m,n] = sum_k A[m*lda+k] * B[n*ldb+k]
// Tile 128x128, BK=64, 256 threads, DOUBLE-BUFFERED LDS (64KB, 2 blocks/CU).
// One barrier/iter. 717 TF measured. PROVEN 2-barrier structure — rounds
// 9/10/11 (depth-2 pipe, hand 8-phase, faithful m201 8-phase port) ALL
// landed at 480-717 TF -> structure experiments closed; this kernel stays.
//
// TAG: dummy template param -> unique mangled symbol per pipeline step so
// rocprof attributes each dispatch separately (steps 2/3 previously shared
// one symbol; per-step budget was unknown).
//
// SWAPXY (round-12, XCD L2 locality): with grid (x=bn), linear id%8 = bn%8
// -> blocks sharing the SMALL B-panel co-locate per XCD while the 16.8MB
// A operand scatters: per-XCD A working set 8MB > 4MB L2 -> thrash ->
// measured FETCH 67.6MB vs 21MB unique input (3.2x over-fetch). SWAPXY=1
// launches grid (x=bm, y=bn): id%8 = bm%8 -> same-A-panel blocks per XCD
// (2MB working set, fits L2); B (4.2MB) streams/L3.
//
// LDS layout: rows of 8 16B-chunks, chunk q of row r at slot q ^ (r&7)
// (XOR swizzle): per-row-contiguous global reads + conflict-free
// ds_read_b128 (measured SQ_LDS_BANK_CONFLICT = 0).
// ---------------------------------------------------------------------------
template <typename OutT, int TAG, int SWAPXY>
__global__ __launch_bounds__(256)
void gemm_nt(const bf16_t* __restrict__ A, const bf16_t* __restrict__ B,
             OutT* __restrict__ C, int K, int lda, int ldb, int ldc)
{
  const int bm = SWAPXY ? blockIdx.x : blockIdx.y;
  const int bn = SWAPXY ? blockIdx.y : blockIdx.x;
  const int m0 = bm * 128, n0 = bn * 128;

  __shared__ bf16_t As[2][128 * 64];  // 16KB each
  __shared__ bf16_t Bs[2][128 * 64];

  const int tid = threadIdx.x;
  const int wave = tid >> 6, lane = tid & 63;
  const int lm = lane & 15, qd = lane >> 4;
  const int wm = (wave >> 1) * 64, wn = (wave & 1) * 64;

  const int rowl = lane >> 3;           // 0..7
  const int q = (lane & 7) ^ rowl;      // swizzled chunk within row
  const bf16_t* Abase = A + (long)(m0 + wave * 8 + rowl) * lda + q * 8;
  const bf16_t* Bbase = B + (long)(n0 + wave * 8 + rowl) * ldb + q * 8;
  const int woff = wave * 512;

  auto stage = [&](int k0, int b) {
#pragma unroll
    for (int i = 0; i < 4; i++) {
      __builtin_amdgcn_global_load_lds((const AS1 void*)(Abase + (long)i * 32 * lda + k0),
                                       (AS3 void*)(As[b] + woff + i * 2048), 16, 0, 0);
      __builtin_amdgcn_global_load_lds((const AS1 void*)(Bbase + (long)i * 32 * ldb + k0),
                                       (AS3 void*)(Bs[b] + woff + i * 2048), 16, 0, 0);
    }
  };

  f32x4 acc[4][4] = {};

  stage(0, 0);
  int buf = 0;
  for (int k0 = 0; k0 < K; k0 += 64) {
    __syncthreads();                   // drains tile-k loads (issued 1 iter ago)
    if (k0 + 64 < K) stage(k0 + 64, buf ^ 1);
#pragma unroll
    for (int s = 0; s < 2; s++) {
      bf16x8 aF[4], bF[4];
#pragma unroll
      for (int i = 0; i < 4; i++) {
        const int r = wm + i * 16 + lm;
        aF[i] = *(const bf16x8*)&As[buf][r * 64 + (((s * 4 + qd) ^ (lm & 7)) << 3)];
      }
#pragma unroll
      for (int j = 0; j < 4; j++) {
        const int r = wn + j * 16 + lm;
        bF[j] = *(const bf16x8*)&Bs[buf][r * 64 + (((s * 4 + qd) ^ (lm & 7)) << 3)];
      }
#pragma unroll
      for (int i = 0; i < 4; i++)
#pragma unroll
        for (int j = 0; j < 4; j++)
          acc[i][j] = __builtin_amdgcn_mfma_f32_16x16x32_bf16(aF[i], bF[j], acc[i][j], 0, 0, 0);
    }
    buf ^= 1;
  }

#pragma unroll
  for (int i = 0; i < 4; i++) {
    const int row = m0 + wm + i * 16 + qd * 4;
#pragma unroll
    for (int j = 0; j < 4; j++) {
      const int col = n0 + wn + j * 16 + lm;
#pragma unroll
      for (int r = 0; r < 4; r++)
        C[(long)(row + r) * ldc + col] = (OutT)acc[i][j][r];
    }
  }
}

// ---------------------------------------------------------------------------
// Causal 128x128 NT GEMM — identical structure to gemm_nt plus batch strides
// and two causal modes. 128 tiles (NOT 256): causal work is load-imbalanced;
// per-block work must stay small (round-11: 256-tile causal had a 268 MF
// diagonal block = 44us single-CU makespan).
//
// causal=1:  skip block if bn > bm (S = QK^T lower-triangle 128-tiles).
// kLimit=1:  Keff = min(K, (bm+1)*128), bm flipped heavy-first. Matches
//            softmax's 128-granular zero-fill -> no uninitialized P reads.
// TAG: unique symbol per step (4 = QK^T, 6 = PV) for rocprof attribution.
// ---------------------------------------------------------------------------
template <typename OutT, int TAG>
__global__ __launch_bounds__(256)
void gemm_ntc(const bf16_t* __restrict__ A, const bf16_t* __restrict__ B,
              OutT* __restrict__ C, int K, int lda, int ldb, int ldc,
              long sA, long sB, long sC, int causal, int kLimit)
{
  int bm = blockIdx.y;
  const int bn = blockIdx.x;
  if (kLimit) bm = gridDim.y - 1 - bm;   // heavy tiles dispatch first
  if (causal && bn > bm) return;
  A += (long)blockIdx.z * sA;
  B += (long)blockIdx.z * sB;
  C += (long)blockIdx.z * sC;
  const int m0 = bm * 128, n0 = bn * 128;
  int Keff = K;
  if (kLimit) { const int kl = (bm + 1) * 128; if (kl < Keff) Keff = kl; }

  __shared__ bf16_t As[2][128 * 64];  // 16KB each
  __shared__ bf16_t Bs[2][128 * 64];

  const int tid = threadIdx.x;
  const int wave = tid >> 6, lane = tid & 63;
  const int lm = lane & 15, qd = lane >> 4;
  const int wm = (wave >> 1) * 64, wn = (wave & 1) * 64;

  const int rowl = lane >> 3;           // 0..7
  const int q = (lane & 7) ^ rowl;      // swizzled chunk within row
  const bf16_t* Abase = A + (long)(m0 + wave * 8 + rowl) * lda + q * 8;
  const bf16_t* Bbase = B + (long)(n0 + wave * 8 + rowl) * ldb + q * 8;
  const int woff = wave * 512;

  auto stage = [&](int k0, int b) {
#pragma unroll
    for (int i = 0; i < 4; i++) {
      __builtin_amdgcn_global_load_lds((const AS1 void*)(Abase + (long)i * 32 * lda + k0),
                                       (AS3 void*)(As[b] + woff + i * 2048), 16, 0, 0);
      __builtin_amdgcn_global_load_lds((const AS1 void*)(Bbase + (long)i * 32 * ldb + k0),
                                       (AS3 void*)(Bs[b] + woff + i * 2048), 16, 0, 0);
    }
  };

  f32x4 acc[4][4] = {};

  stage(0, 0);
  int buf = 0;
  for (int k0 = 0; k0 < Keff; k0 += 64) {
    __syncthreads();                   // drains tile-k loads (issued 1 iter ago)
    if (k0 + 64 < Keff) stage(k0 + 64, buf ^ 1);
#pragma unroll
    for (int s = 0; s < 2; s++) {
      bf16x8 aF[4], bF[4];
#pragma unroll
      for (int i = 0; i < 4; i++) {
        const int r = wm + i * 16 + lm;
        aF[i] = *(const bf16x8*)&As[buf][r * 64 + (((s * 4 + qd) ^ (lm & 7)) << 3)];
      }
#pragma unroll
      for (int j = 0; j < 4; j++) {
        const int r = wn + j * 16 + lm;
        bF[j] = *(const bf16x8*)&Bs[buf][r * 64 + (((s * 4 + qd) ^ (lm & 7)) << 3)];
      }
#pragma unroll
      for (int i = 0; i < 4; i++)
#pragma unroll
        for (int j = 0; j < 4; j++)
          acc[i][j] = __builtin_amdgcn_mfma_f32_16x16x32_bf16(aF[i], bF[j], acc[i][j], 0, 0, 0);
    }
    buf ^= 1;
  }

#pragma unroll
  for (int i = 0; i < 4; i++) {
    const int row = m0 + wm + i * 16 + qd * 4;
#pragma unroll
    for (int j = 0; j < 4; j++) {
      const int col = n0 + wn + j * 16 + lm;
#pragma unroll
      for (int r = 0; r < 4; r++)
        C[(long)(row + r) * ldc + col] = (OutT)acc[i][j][r];
    }
  }
}

// ---------------------------------------------------------------------------
// Fused prep (ONE dispatch): blocks [0,8192) convert X fp32->bf16 (float4
// loads); blocks [8192, 8192+3072) transpose+convert Wq/Wk/Wv into
// WT[out][in] bf16 (32x32 tiles, 256 threads, 4 rows/thread).
// ---------------------------------------------------------------------------
__global__ __launch_bounds__(256)
void prep(const float* __restrict__ X, bf16_t* __restrict__ Xb,
          const float* __restrict__ wq, const float* __restrict__ wk,
          const float* __restrict__ wv, bf16_t* __restrict__ WT)
{
  const int b = blockIdx.x;
  if (b < 8192) {                       // X -> bf16, 4 floats/thread
    const int i = b * 256 + threadIdx.x;
    const float4 f = ((const float4*)X)[i];
    bf16x4 o = {(bf16_t)f.x, (bf16_t)f.y, (bf16_t)f.z, (bf16_t)f.w};
    ((bf16x4*)Xb)[i] = o;
    return;
  }
  const int wid = b - 8192;             // 0..3071
  const int z = wid >> 10;              // which W
  const int t = wid & 1023;             // tile id, 32x32 grid of 32x32 tiles
  const int tix = t & 31, tiy = t >> 5;
  const float* W = (z == 0) ? wq : (z == 1) ? wk : wv;
  bf16_t* O = WT + (long)z * 1024 * 1024;

  __shared__ float tile[32][33];
  const int x = threadIdx.x & 31, y0 = threadIdx.x >> 5;
#pragma unroll
  for (int r = 0; r < 4; r++) {         // read: coalesced over out dim (x)
    const int y = y0 + r * 8;
    tile[y][x] = W[(long)(tiy * 32 + y) * 1024 + (tix * 32 + x)];
  }
  __syncthreads();
#pragma unroll
  for (int r = 0; r < 4; r++) {         // write: coalesced over in dim (x)
    const int y = y0 + r * 8;
    O[(long)(tix * 32 + y) * 1024 + (tiy * 32 + x)] = (bf16_t)tile[x][y];
  }
}

// ---------------------------------------------------------------------------
// In-place causal softmax over S rows (bf16, ld=2048). One block per row.
// logits = S/32; writes P = softmax, zeros above the diagonal.
// Loads only j <= t; stores only j < kend = ((t>>7)+1)*128 — beyond kend P
// is never read by the PV GEMM (Keff stops there); [t+1, kend) gets zeros.
// ---------------------------------------------------------------------------
__global__ __launch_bounds__(256)
void softmax_causal(bf16_t* __restrict__ S)
{
  const int row = blockIdx.x;
  const int t = row & 2047;
  const int kend = ((t >> 7) + 1) << 7;
  bf16_t* Sr = S + (long)row * 2048;
  const int base = threadIdx.x * 8;

  uint4 u = {0, 0, 0, 0};
  if (base <= t) u = *(const uint4*)(Sr + base);
  const unsigned short* up = (const unsigned short*)&u;
  float v[8];
  float m = -3.0e38f;
#pragma unroll
  for (int j = 0; j < 8; j++) {
    const float x = __uint_as_float(((unsigned)up[j]) << 16);  // bf16 -> f32
    v[j] = (base + j <= t) ? x : -3.0e38f;
    m = fmaxf(m, v[j]);
  }
#pragma unroll
  for (int off = 32; off > 0; off >>= 1) m = fmaxf(m, __shfl_xor(m, off));
  __shared__ float redm[4], redl[4];
  const int wave = threadIdx.x >> 6, lane = threadIdx.x & 63;
  if (lane == 0) redm[wave] = m;
  __syncthreads();
  m = fmaxf(fmaxf(redm[0], redm[1]), fmaxf(redm[2], redm[3]));

  float p[8], l = 0.f;
#pragma unroll
  for (int j = 0; j < 8; j++) {
    p[j] = (base + j <= t) ? __expf((v[j] - m) * 0.03125f) : 0.f;
    l += p[j];
  }
#pragma unroll
  for (int off = 32; off > 0; off >>= 1) l += __shfl_xor(l, off);
  if (lane == 0) redl[wave] = l;
  __syncthreads();
  l = (redl[0] + redl[1]) + (redl[2] + redl[3]);
  const float rl = 1.0f / l;

  if (base < kend) {
    uint4 w;
    unsigned* wp = (unsigned*)&w;
#pragma unroll
    for (int h = 0; h < 4; h++) {
      bf16_t a = (bf16_t)(p[2 * h] * rl);
      bf16_t b = (bf16_t)(p[2 * h + 1] * rl);
      wp[h] = (unsigned)__builtin_bit_cast(unsigned short, a) |
              ((unsigned)__builtin_bit_cast(unsigned short, b) << 16);
    }
    *(uint4*)(Sr + base) = w;
  }
}

// ---------------------------------------------------------------------------
extern "C" void kernel_launch(void* const* d_in, const int* in_sizes, int n_in,
                              void* d_out, int out_size, void* d_ws, size_t ws_size,
                              hipStream_t stream)
{
  const float* X  = (const float*)d_in[0];  // [4,2048,1024]
  const float* Wq = (const float*)d_in[1];  // [1024,1024] (in,out)
  const float* Wk = (const float*)d_in[2];
  const float* Wv = (const float*)d_in[3];
  float* out = (float*)d_out;               // [4,2048,1024]

  // workspace layout (bytes): QK 33.5M | VT 16.8M | WT 6.3M | {Xb 16.8M / S 33.5M overlap}
  char* p = (char*)d_ws;
  bf16_t* QK = (bf16_t*)p;  p += (size_t)8192 * 2048 * 2;   // [8192, 2048]  Q|K
  bf16_t* VT = (bf16_t*)p;  p += (size_t)1024 * 8192 * 2;   // [1024, 8192]  V^T
  bf16_t* WT = (bf16_t*)p;  p += (size_t)3072 * 1024 * 2;   // [3072, 1024]  Wq^T|Wk^T|Wv^T
  bf16_t* Xb = (bf16_t*)p;                                  // [8192, 1024]  (dead before S)
  bf16_t* S  = (bf16_t*)p;                                  // [4][2048,2048] scores->P

  // 1) fused prep: X -> bf16  +  W -> WT (bf16, transposed)
  prep<<<8192 + 3072, 256, 0, stream>>>(X, Xb, Wq, Wk, Wv, WT);
  // 2) QK = Xb @ [Wq|Wk]   M=8192 N=2048 K=1024   (1024 blocks)
  //    SWAPXY grid (x=bm=64, y=bn=16): same-A-panel blocks co-locate per XCD
  //    (id%8 = bm%8); per-XCD A working set 2MB fits L2 (was 8MB thrash).
  gemm_nt<bf16_t, 2, 1><<<dim3(64, 16), 256, 0, stream>>>(
      Xb, WT, QK, 1024, 1024, 1024, 2048);
  // 3) VT = WvT @ Xb^T     M=1024 N=8192 K=1024   (512 blocks; id%8=bn%8
  //    already co-locates the big-B (Xb) panels -> keep mapping)
  gemm_nt<bf16_t, 3, 0><<<dim3(64, 8), 256, 0, stream>>>(
      WT + (long)2048 * 1024, Xb, VT, 1024, 1024, 1024, 8192);
  // 4) S = Q @ K^T per batch, 128x128 lower-tri tiles (544 active)
  gemm_ntc<bf16_t, 4><<<dim3(16, 16, 4), 256, 0, stream>>>(
      QK, QK + 1024, S, 1024, 2048, 2048, 2048,
      (long)2048 * 2048, (long)2048 * 2048, (long)2048 * 2048, 1, 0);
  // 5) in-place causal softmax (128-granular truncated IO)
  softmax_causal<<<8192, 256, 0, stream>>>(S);
  // 6) O = P @ V (NT vs V^T), 128-row tiles, Keff=(bm+1)*128, heavy-first
  gemm_ntc<float, 6><<<dim3(8, 16, 4), 256, 0, stream>>>(
      S, VT, out, 2048, 2048, 8192, 1024,
      (long)2048 * 2048, 2048, (long)2048 * 1024, 0, 1);
}